// Round 1
// baseline (8513.716 us; speedup 1.0000x reference)
//
#include <hip/hip_runtime.h>
#include <hip/hip_bf16.h>

#define BB 128
#define LL 200
#define DD 512
#define HH 8
#define DK 64
#define NBLK 2
#define BL (BB*LL)

// ---------------- masks ----------------
__global__ __launch_bounds__(256) void mask_kernel(const int* __restrict__ logs,
                                                   const int* __restrict__ entire,
                                                   float* __restrict__ tlf,
                                                   float* __restrict__ keepf,
                                                   float* __restrict__ kmf) {
    int i = blockIdx.x * 256 + threadIdx.x;
    if (i < BL) {
        float t = (logs[i] == 0) ? 1.f : 0.f;
        tlf[i] = t;
        keepf[i] = 1.f - t;
        kmf[i] = (logs[i] == 0 && entire[i] != 0) ? 1.f : 0.f;
    }
}

// target = seqs_embs * keep   (one block per row)
__global__ __launch_bounds__(256) void init_target(const float* __restrict__ emb,
                                                   const float* __restrict__ keepf,
                                                   float* __restrict__ tgt) {
    int row = blockIdx.x;
    int t = threadIdx.x;
    float kf = keepf[row];
    size_t base = (size_t)row * DD;
    tgt[base + t] = emb[base + t] * kf;
    tgt[base + t + 256] = emb[base + t + 256] * kf;
}

// ---------------- layernorm (block per row, 512 elems, 2/thread) ----------------
// out = LN(x [+ addx]) * (keepf ? keep : 1)
__global__ __launch_bounds__(256) void ln_kernel(const float* __restrict__ x,
                                                 const float* __restrict__ addx,
                                                 float* __restrict__ out,
                                                 const float* __restrict__ g,
                                                 const float* __restrict__ bt,
                                                 const float* __restrict__ keepf) {
    int row = blockIdx.x;
    int t = threadIdx.x;
    size_t base = (size_t)row * DD;
    float v0 = x[base + t], v1 = x[base + t + 256];
    if (addx) { v0 += addx[base + t]; v1 += addx[base + t + 256]; }
    float s = v0 + v1, sq = v0 * v0 + v1 * v1;
    #pragma unroll
    for (int off = 32; off; off >>= 1) {
        s += __shfl_xor(s, off);
        sq += __shfl_xor(sq, off);
    }
    __shared__ float rs[4], rq[4];
    int wid = t >> 6, lane = t & 63;
    if (lane == 0) { rs[wid] = s; rq[wid] = sq; }
    __syncthreads();
    s = rs[0] + rs[1] + rs[2] + rs[3];
    sq = rq[0] + rq[1] + rq[2] + rq[3];
    float mean = s * (1.f / DD);
    float var = sq * (1.f / DD) - mean * mean;
    float rstd = rsqrtf(fmaxf(var, 0.f) + 1e-8f);
    float kf = keepf ? keepf[row] : 1.f;
    out[base + t] = ((v0 - mean) * rstd * g[t] + bt[t]) * kf;
    out[base + t + 256] = ((v1 - mean) * rstd * g[t + 256] + bt[t + 256]) * kf;
}

// ---------------- GEMM: C[M,N] = epilogue(A[M,K] @ W[K,N] + bias) ----------------
// rowscale: if non-null, A row r scaled by rowscale[r] (source masking).
// mode 0: store; mode 1: relu store; mode 2: C = (C + acc + bias) * keepf[row]
#define BM 64
#define BN 64
#define BK 32
__global__ __launch_bounds__(256) void gemm_kernel(const float* __restrict__ A,
                                                   const float* __restrict__ W,
                                                   const float* __restrict__ bias,
                                                   float* __restrict__ C,
                                                   const float* __restrict__ rowscale,
                                                   const float* __restrict__ keepf,
                                                   int mode, int M, int N, int K) {
    __shared__ float sA[BK][BM + 4];   // sA[k][m]
    __shared__ float sW[BK][BN + 4];   // sW[k][n]
    int t = threadIdx.x;
    int tx = t & 15, ty = t >> 4;
    int m0 = blockIdx.x * BM, n0 = blockIdx.y * BN;
    float acc[4][4] = {};
    for (int k0 = 0; k0 < K; k0 += BK) {
        #pragma unroll
        for (int i = 0; i < 2; i++) {
            int f = t + i * 256;
            int r = f >> 3, c4 = f & 7;
            float4 av = *(const float4*)(A + (size_t)(m0 + r) * K + k0 + c4 * 4);
            if (rowscale) {
                float sc = rowscale[m0 + r];
                av.x *= sc; av.y *= sc; av.z *= sc; av.w *= sc;
            }
            sA[c4 * 4 + 0][r] = av.x;
            sA[c4 * 4 + 1][r] = av.y;
            sA[c4 * 4 + 2][r] = av.z;
            sA[c4 * 4 + 3][r] = av.w;
        }
        #pragma unroll
        for (int i = 0; i < 2; i++) {
            int f = t + i * 256;
            int r = f >> 4, c4 = f & 15;
            float4 wv = *(const float4*)(W + (size_t)(k0 + r) * N + n0 + c4 * 4);
            *(float4*)(&sW[r][c4 * 4]) = wv;
        }
        __syncthreads();
        #pragma unroll
        for (int kk = 0; kk < BK; kk++) {
            float4 a4 = *(const float4*)(&sA[kk][ty * 4]);
            float4 b4 = *(const float4*)(&sW[kk][tx * 4]);
            float ar[4] = {a4.x, a4.y, a4.z, a4.w};
            float br[4] = {b4.x, b4.y, b4.z, b4.w};
            #pragma unroll
            for (int i = 0; i < 4; i++)
                #pragma unroll
                for (int j = 0; j < 4; j++)
                    acc[i][j] = fmaf(ar[i], br[j], acc[i][j]);
        }
        __syncthreads();
    }
    float4 bb = *(const float4*)(bias + n0 + tx * 4);
    #pragma unroll
    for (int i = 0; i < 4; i++) {
        int row = m0 + ty * 4 + i;
        float4 o;
        o.x = acc[i][0] + bb.x;
        o.y = acc[i][1] + bb.y;
        o.z = acc[i][2] + bb.z;
        o.w = acc[i][3] + bb.w;
        float* cp = C + (size_t)row * N + n0 + tx * 4;
        if (mode == 1) {
            o.x = fmaxf(o.x, 0.f); o.y = fmaxf(o.y, 0.f);
            o.z = fmaxf(o.z, 0.f); o.w = fmaxf(o.w, 0.f);
        } else if (mode == 2) {
            float kf = keepf[row];
            float4 old = *(const float4*)cp;
            o.x = (old.x + o.x) * kf; o.y = (old.y + o.y) * kf;
            o.z = (old.z + o.z) * kf; o.w = (old.w + o.w) * kf;
        }
        *(float4*)cp = o;
    }
}

// ---------------- attention: one wave per (b, h, query) ----------------
__global__ __launch_bounds__(256) void attn_kernel(const float* __restrict__ q,
                                                   const float* __restrict__ k,
                                                   const float* __restrict__ v,
                                                   const float* __restrict__ kmf,
                                                   float* __restrict__ xout) {
    __shared__ float sp[4][LL];
    int wid = threadIdx.x >> 6, lane = threadIdx.x & 63;
    int row = blockIdx.x * 4 + wid;       // in [0, B*H*L)
    int qi = row % LL;
    int bh = row / LL;
    int h = bh % HH;
    int b = bh / HH;
    const float scale = 0.125f;           // 1/sqrt(64)

    float qd = q[((size_t)b * LL + qi) * DD + h * DK + lane];

    // scores
    for (int j = 0; j < LL; j++) {
        float kd = k[((size_t)b * LL + j) * DD + h * DK + lane];
        float s = qd * kd;
        #pragma unroll
        for (int off = 32; off; off >>= 1) s += __shfl_xor(s, off);
        bool m = (j <= qi) && (kmf[b * LL + j] != 0.f);
        if (lane == 0) sp[wid][j] = m ? s * scale : -1e9f;
    }
    __syncthreads();

    // softmax over all L entries (then mask-multiply, matching reference)
    float lm = -3.0e38f;
    for (int j = lane; j < LL; j += 64) lm = fmaxf(lm, sp[wid][j]);
    #pragma unroll
    for (int off = 32; off; off >>= 1) lm = fmaxf(lm, __shfl_xor(lm, off));
    float ls = 0.f;
    for (int j = lane; j < LL; j += 64) {
        float e = __expf(sp[wid][j] - lm);
        sp[wid][j] = e;
        ls += e;
    }
    #pragma unroll
    for (int off = 32; off; off >>= 1) ls += __shfl_xor(ls, off);
    float inv = 1.f / ls;
    __syncthreads();
    for (int j = lane; j < LL; j += 64) {
        bool m = (j <= qi) && (kmf[b * LL + j] != 0.f);
        sp[wid][j] = m ? sp[wid][j] * inv : 0.f;
    }
    __syncthreads();

    // PV
    float acc = 0.f;
    for (int j = 0; j < LL; j++) {
        acc = fmaf(sp[wid][j], v[((size_t)b * LL + j) * DD + h * DK + lane], acc);
    }
    xout[((size_t)b * LL + qi) * DD + h * DK + lane] = acc;
}

extern "C" void kernel_launch(void* const* d_in, const int* in_sizes, int n_in,
                              void* d_out, int out_size, void* d_ws, size_t ws_size,
                              hipStream_t stream) {
    const int* log_seqs = (const int*)d_in[0];
    const float* seqs_embs = (const float*)d_in[1];
    const int* entire = (const int*)d_in[2];
    const float* Wq = (const float*)d_in[3];
    const float* bq = (const float*)d_in[4];
    const float* Wk = (const float*)d_in[5];
    const float* bk = (const float*)d_in[6];
    const float* Wv = (const float*)d_in[7];
    const float* bv = (const float*)d_in[8];
    const float* lag = (const float*)d_in[9];
    const float* lab = (const float*)d_in[10];
    const float* lfg = (const float*)d_in[11];
    const float* lfb = (const float*)d_in[12];
    const float* W1 = (const float*)d_in[13];
    const float* b1 = (const float*)d_in[14];
    const float* W2 = (const float*)d_in[15];
    const float* b2 = (const float*)d_in[16];
    const float* llg = (const float*)d_in[17];
    const float* llb = (const float*)d_in[18];
    float* out = (float*)d_out;
    float* ws = (float*)d_ws;

    const size_t n = (size_t)BL * DD;
    float* tgt = ws;
    float* qb = ws + n;
    float* kb = ws + 2 * n;
    float* vb = ws + 3 * n;
    float* ab = ws + 4 * n;          // qn, then attention output x
    float* tlf = ws + 5 * n;
    float* keepf = tlf + BL;
    float* kmf = keepf + BL;

    mask_kernel<<<(BL + 255) / 256, 256, 0, stream>>>(log_seqs, entire, tlf, keepf, kmf);
    init_target<<<BL, 256, 0, stream>>>(seqs_embs, keepf, tgt);

    dim3 ggrid(BL / BM, DD / BN);
    for (int i = 0; i < NBLK; i++) {
        // qn = LN(target, ln_attn)
        ln_kernel<<<BL, 256, 0, stream>>>(tgt, nullptr, ab, lag + i * DD, lab + i * DD, nullptr);
        // q = qn @ Wq + bq
        gemm_kernel<<<ggrid, 256, 0, stream>>>(ab, Wq + i * DD * DD, bq + i * DD, qb,
                                               nullptr, nullptr, 0, BL, DD, DD);
        // k = (emb * tl) @ Wk + bk ; v likewise
        gemm_kernel<<<ggrid, 256, 0, stream>>>(seqs_embs, Wk + i * DD * DD, bk + i * DD, kb,
                                               tlf, nullptr, 0, BL, DD, DD);
        gemm_kernel<<<ggrid, 256, 0, stream>>>(seqs_embs, Wv + i * DD * DD, bv + i * DD, vb,
                                               tlf, nullptr, 0, BL, DD, DD);
        // x = attention(q,k,v)  -> ab
        attn_kernel<<<(BB * HH * LL) / 4, 256, 0, stream>>>(qb, kb, vb, kmf, ab);
        // target = LN(x (+ target if i>0), ln_fwd)
        ln_kernel<<<BL, 256, 0, stream>>>(ab, (i == 0) ? nullptr : tgt, tgt,
                                          lfg + i * DD, lfb + i * DD, nullptr);
        // h = relu(target @ W1 + b1)   (reuse qb)
        gemm_kernel<<<ggrid, 256, 0, stream>>>(tgt, W1 + i * DD * DD, b1 + i * DD, qb,
                                               nullptr, nullptr, 1, BL, DD, DD);
        // target = (target + h @ W2 + b2) * keep
        gemm_kernel<<<ggrid, 256, 0, stream>>>(qb, W2 + i * DD * DD, b2 + i * DD, tgt,
                                               nullptr, keepf, 2, BL, DD, DD);
    }
    // out = LN(target, ln_last) * keep
    ln_kernel<<<BL, 256, 0, stream>>>(tgt, nullptr, out, llg, llb, keepf);
}

// Round 2
// 2868.130 us; speedup vs baseline: 2.9684x; 2.9684x over previous
//
#include <hip/hip_runtime.h>
#include <hip/hip_bf16.h>

#define BB 128
#define LL 200
#define DD 512
#define HH 8
#define DK 64
#define NBLK 2
#define BL (BB*LL)

// ---------------- masks ----------------
__global__ __launch_bounds__(256) void mask_kernel(const int* __restrict__ logs,
                                                   const int* __restrict__ entire,
                                                   float* __restrict__ tlf,
                                                   float* __restrict__ keepf,
                                                   float* __restrict__ kmf) {
    int i = blockIdx.x * 256 + threadIdx.x;
    if (i < BL) {
        float t = (logs[i] == 0) ? 1.f : 0.f;
        tlf[i] = t;
        keepf[i] = 1.f - t;
        kmf[i] = (logs[i] == 0 && entire[i] != 0) ? 1.f : 0.f;
    }
}

// target = seqs_embs * keep   (one block per row)
__global__ __launch_bounds__(256) void init_target(const float* __restrict__ emb,
                                                   const float* __restrict__ keepf,
                                                   float* __restrict__ tgt) {
    int row = blockIdx.x;
    int t = threadIdx.x;
    float kf = keepf[row];
    size_t base = (size_t)row * DD;
    tgt[base + t] = emb[base + t] * kf;
    tgt[base + t + 256] = emb[base + t + 256] * kf;
}

// ---------------- layernorm (block per row, 512 elems, 2/thread) ----------------
__global__ __launch_bounds__(256) void ln_kernel(const float* __restrict__ x,
                                                 const float* __restrict__ addx,
                                                 float* __restrict__ out,
                                                 const float* __restrict__ g,
                                                 const float* __restrict__ bt,
                                                 const float* __restrict__ keepf) {
    int row = blockIdx.x;
    int t = threadIdx.x;
    size_t base = (size_t)row * DD;
    float v0 = x[base + t], v1 = x[base + t + 256];
    if (addx) { v0 += addx[base + t]; v1 += addx[base + t + 256]; }
    float s = v0 + v1, sq = v0 * v0 + v1 * v1;
    #pragma unroll
    for (int off = 32; off; off >>= 1) {
        s += __shfl_xor(s, off);
        sq += __shfl_xor(sq, off);
    }
    __shared__ float rs[4], rq[4];
    int wid = t >> 6, lane = t & 63;
    if (lane == 0) { rs[wid] = s; rq[wid] = sq; }
    __syncthreads();
    s = rs[0] + rs[1] + rs[2] + rs[3];
    sq = rq[0] + rq[1] + rq[2] + rq[3];
    float mean = s * (1.f / DD);
    float var = sq * (1.f / DD) - mean * mean;
    float rstd = rsqrtf(fmaxf(var, 0.f) + 1e-8f);
    float kf = keepf ? keepf[row] : 1.f;
    out[base + t] = ((v0 - mean) * rstd * g[t] + bt[t]) * kf;
    out[base + t + 256] = ((v1 - mean) * rstd * g[t + 256] + bt[t + 256]) * kf;
}

// ---------------- GEMM: C[M,N] = epilogue(A[M,K] @ W[K,N] + bias) ----------------
#define BM 64
#define BN 64
#define BK 32
__global__ __launch_bounds__(256) void gemm_kernel(const float* __restrict__ A,
                                                   const float* __restrict__ W,
                                                   const float* __restrict__ bias,
                                                   float* __restrict__ C,
                                                   const float* __restrict__ rowscale,
                                                   const float* __restrict__ keepf,
                                                   int mode, int M, int N, int K) {
    __shared__ float sA[BK][BM + 4];   // sA[k][m]
    __shared__ float sW[BK][BN + 4];   // sW[k][n]
    int t = threadIdx.x;
    int tx = t & 15, ty = t >> 4;
    int m0 = blockIdx.x * BM, n0 = blockIdx.y * BN;
    float acc[4][4] = {};
    for (int k0 = 0; k0 < K; k0 += BK) {
        #pragma unroll
        for (int i = 0; i < 2; i++) {
            int f = t + i * 256;
            int r = f >> 3, c4 = f & 7;
            float4 av = *(const float4*)(A + (size_t)(m0 + r) * K + k0 + c4 * 4);
            if (rowscale) {
                float sc = rowscale[m0 + r];
                av.x *= sc; av.y *= sc; av.z *= sc; av.w *= sc;
            }
            sA[c4 * 4 + 0][r] = av.x;
            sA[c4 * 4 + 1][r] = av.y;
            sA[c4 * 4 + 2][r] = av.z;
            sA[c4 * 4 + 3][r] = av.w;
        }
        #pragma unroll
        for (int i = 0; i < 2; i++) {
            int f = t + i * 256;
            int r = f >> 4, c4 = f & 15;
            float4 wv = *(const float4*)(W + (size_t)(k0 + r) * N + n0 + c4 * 4);
            *(float4*)(&sW[r][c4 * 4]) = wv;
        }
        __syncthreads();
        #pragma unroll
        for (int kk = 0; kk < BK; kk++) {
            float4 a4 = *(const float4*)(&sA[kk][ty * 4]);
            float4 b4 = *(const float4*)(&sW[kk][tx * 4]);
            float ar[4] = {a4.x, a4.y, a4.z, a4.w};
            float br[4] = {b4.x, b4.y, b4.z, b4.w};
            #pragma unroll
            for (int i = 0; i < 4; i++)
                #pragma unroll
                for (int j = 0; j < 4; j++)
                    acc[i][j] = fmaf(ar[i], br[j], acc[i][j]);
        }
        __syncthreads();
    }
    float4 bb = *(const float4*)(bias + n0 + tx * 4);
    #pragma unroll
    for (int i = 0; i < 4; i++) {
        int row = m0 + ty * 4 + i;
        float4 o;
        o.x = acc[i][0] + bb.x;
        o.y = acc[i][1] + bb.y;
        o.z = acc[i][2] + bb.z;
        o.w = acc[i][3] + bb.w;
        float* cp = C + (size_t)row * N + n0 + tx * 4;
        if (mode == 1) {
            o.x = fmaxf(o.x, 0.f); o.y = fmaxf(o.y, 0.f);
            o.z = fmaxf(o.z, 0.f); o.w = fmaxf(o.w, 0.f);
        } else if (mode == 2) {
            float kf = keepf[row];
            float4 old = *(const float4*)cp;
            o.x = (old.x + o.x) * kf; o.y = (old.y + o.y) * kf;
            o.z = (old.z + o.z) * kf; o.w = (old.w + o.w) * kf;
        }
        *(float4*)cp = o;
    }
}

// ---------------- attention v2: one workgroup per (b,h) ----------------
// LDS (floats): kT[64][200] @0 | S[200][64] @12800 | shr(qT[64][64]/Vs[200][64]) @25600
//               kms[208] @38400 | red[4][64] @38608  -> total 38864 floats = 155456 B
#define ATTN_LDS_FLOATS 38864
__global__ __launch_bounds__(256, 1) void attn2_kernel(const float* __restrict__ q,
                                                       const float* __restrict__ k,
                                                       const float* __restrict__ v,
                                                       const float* __restrict__ kmf,
                                                       float* __restrict__ xout) {
    extern __shared__ float lds[];
    float* kT  = lds;             // [64][200]  kT[d*200+j]
    float* S   = lds + 12800;     // [200][64]  S[j*64+qi]
    float* shr = lds + 25600;     // qT[d*64+qi] then Vs[j*64+d]
    float* kms = lds + 38400;     // [200]
    float* red = lds + 38608;     // [4][64]

    int t = threadIdx.x;
    int b = blockIdx.x >> 3;
    int h = blockIdx.x & 7;
    int tx = t & 15, ty = t >> 4;
    int wv = t >> 6, lane = t & 63;

    const float* kbase = k + (size_t)b * LL * DD + h * DK;
    const float* vbase = v + (size_t)b * LL * DD + h * DK;
    const float* qbase = q + (size_t)b * LL * DD + h * DK;
    float* obase = xout + (size_t)b * LL * DD + h * DK;

    // stage K^T (transpose during store) + key mask
    for (int idx = t; idx < LL * 16; idx += 256) {
        int j = idx >> 4, dq = idx & 15;
        float4 kv = *(const float4*)(kbase + (size_t)j * DD + dq * 4);
        kT[(dq * 4 + 0) * 200 + j] = kv.x;
        kT[(dq * 4 + 1) * 200 + j] = kv.y;
        kT[(dq * 4 + 2) * 200 + j] = kv.z;
        kT[(dq * 4 + 3) * 200 + j] = kv.w;
    }
    if (t < LL) kms[t] = kmf[b * LL + t];
    __syncthreads();

    for (int qt = 0; qt < 4; qt++) {
        int q0 = qt * 64;
        int qn = (q0 + 64 <= LL) ? 64 : (LL - q0);
        // stage Q^T tile
        for (int idx = t; idx < qn * 16; idx += 256) {
            int qi = idx >> 4, dq = idx & 15;
            float4 qv = *(const float4*)(qbase + (size_t)(q0 + qi) * DD + dq * 4);
            shr[(dq * 4 + 0) * 64 + qi] = qv.x;
            shr[(dq * 4 + 1) * 64 + qi] = qv.y;
            shr[(dq * 4 + 2) * 64 + qi] = qv.z;
            shr[(dq * 4 + 3) * 64 + qi] = qv.w;
        }
        __syncthreads();

        // GEMM1: S[j][qi] = sum_d K[j][d] * Q[q0+qi][d], then mask+scale
        for (int jp = 0; jp < 4; jp++) {
            int j0 = jp * 64 + ty * 4;
            if (j0 < LL) {
                float acc[4][4] = {};
                #pragma unroll 4
                for (int d = 0; d < 64; d++) {
                    float4 a4 = *(const float4*)(kT + d * 200 + j0);
                    float4 b4 = *(const float4*)(shr + d * 64 + tx * 4);
                    float ar[4] = {a4.x, a4.y, a4.z, a4.w};
                    float br[4] = {b4.x, b4.y, b4.z, b4.w};
                    #pragma unroll
                    for (int i = 0; i < 4; i++)
                        #pragma unroll
                        for (int jj = 0; jj < 4; jj++)
                            acc[i][jj] = fmaf(ar[i], br[jj], acc[i][jj]);
                }
                #pragma unroll
                for (int i = 0; i < 4; i++) {
                    int j = j0 + i;
                    bool km = (kms[j] != 0.f);
                    int qg = q0 + tx * 4;
                    float4 o;
                    o.x = (km && j <= qg + 0) ? acc[i][0] * 0.125f : -1e9f;
                    o.y = (km && j <= qg + 1) ? acc[i][1] * 0.125f : -1e9f;
                    o.z = (km && j <= qg + 2) ? acc[i][2] * 0.125f : -1e9f;
                    o.w = (km && j <= qg + 3) ? acc[i][3] * 0.125f : -1e9f;
                    *(float4*)(S + j * 64 + tx * 4) = o;
                }
            }
        }
        __syncthreads();

        // softmax over keys per column qi; wave wv handles j = wv, wv+4, ...
        {
            int qi = lane;
            float mx = -3e38f;
            for (int j = wv; j < LL; j += 4) mx = fmaxf(mx, S[j * 64 + qi]);
            red[wv * 64 + qi] = mx;
            __syncthreads();
            mx = fmaxf(fmaxf(red[0 * 64 + qi], red[1 * 64 + qi]),
                       fmaxf(red[2 * 64 + qi], red[3 * 64 + qi]));
            __syncthreads();
            float sm = 0.f;
            for (int j = wv; j < LL; j += 4) {
                float e = __expf(S[j * 64 + qi] - mx);
                S[j * 64 + qi] = e;
                sm += e;
            }
            red[wv * 64 + qi] = sm;
            __syncthreads();
            sm = red[0 * 64 + qi] + red[1 * 64 + qi] + red[2 * 64 + qi] + red[3 * 64 + qi];
            // all-masked column (mx == -1e9): reference gives exact zeros
            float inv = (mx < -5e8f) ? 0.f : 1.f / sm;
            for (int j = wv; j < LL; j += 4) S[j * 64 + qi] *= inv;
        }
        __syncthreads();

        // stage V (natural layout) into shr
        for (int idx = t; idx < LL * 16; idx += 256) {
            int j = idx >> 4, dq = idx & 15;
            float4 vv = *(const float4*)(vbase + (size_t)j * DD + dq * 4);
            *(float4*)(shr + j * 64 + dq * 4) = vv;
        }
        __syncthreads();

        // GEMM2: O[qi][d] = sum_j P[j][qi] * V[j][d]
        {
            float acc[4][4] = {};
            #pragma unroll 4
            for (int j = 0; j < LL; j++) {
                float4 a4 = *(const float4*)(S + j * 64 + ty * 4);
                float4 b4 = *(const float4*)(shr + j * 64 + tx * 4);
                float ar[4] = {a4.x, a4.y, a4.z, a4.w};
                float br[4] = {b4.x, b4.y, b4.z, b4.w};
                #pragma unroll
                for (int i = 0; i < 4; i++)
                    #pragma unroll
                    for (int jj = 0; jj < 4; jj++)
                        acc[i][jj] = fmaf(ar[i], br[jj], acc[i][jj]);
            }
            #pragma unroll
            for (int i = 0; i < 4; i++) {
                int qi = ty * 4 + i;
                if (q0 + qi < LL) {
                    float4 o = {acc[i][0], acc[i][1], acc[i][2], acc[i][3]};
                    *(float4*)(obase + (size_t)(q0 + qi) * DD + tx * 4) = o;
                }
            }
        }
        __syncthreads();   // before next tile overwrites shr
    }
}

extern "C" void kernel_launch(void* const* d_in, const int* in_sizes, int n_in,
                              void* d_out, int out_size, void* d_ws, size_t ws_size,
                              hipStream_t stream) {
    const int* log_seqs = (const int*)d_in[0];
    const float* seqs_embs = (const float*)d_in[1];
    const int* entire = (const int*)d_in[2];
    const float* Wq = (const float*)d_in[3];
    const float* bq = (const float*)d_in[4];
    const float* Wk = (const float*)d_in[5];
    const float* bk = (const float*)d_in[6];
    const float* Wv = (const float*)d_in[7];
    const float* bv = (const float*)d_in[8];
    const float* lag = (const float*)d_in[9];
    const float* lab = (const float*)d_in[10];
    const float* lfg = (const float*)d_in[11];
    const float* lfb = (const float*)d_in[12];
    const float* W1 = (const float*)d_in[13];
    const float* b1 = (const float*)d_in[14];
    const float* W2 = (const float*)d_in[15];
    const float* b2 = (const float*)d_in[16];
    const float* llg = (const float*)d_in[17];
    const float* llb = (const float*)d_in[18];
    float* out = (float*)d_out;
    float* ws = (float*)d_ws;

    // allow >64KB dynamic LDS (idempotent, host-side, capture-safe)
    static bool attr_set = false;
    (void)attr_set;
    hipFuncSetAttribute((const void*)attn2_kernel,
                        hipFuncAttributeMaxDynamicSharedMemorySize,
                        ATTN_LDS_FLOATS * 4);

    const size_t n = (size_t)BL * DD;
    float* tgt = ws;
    float* qb = ws + n;
    float* kb = ws + 2 * n;
    float* vb = ws + 3 * n;
    float* ab = ws + 4 * n;
    float* tlf = ws + 5 * n;
    float* keepf = tlf + BL;
    float* kmf = keepf + BL;

    mask_kernel<<<(BL + 255) / 256, 256, 0, stream>>>(log_seqs, entire, tlf, keepf, kmf);
    init_target<<<BL, 256, 0, stream>>>(seqs_embs, keepf, tgt);

    dim3 ggrid(BL / BM, DD / BN);
    for (int i = 0; i < NBLK; i++) {
        ln_kernel<<<BL, 256, 0, stream>>>(tgt, nullptr, ab, lag + i * DD, lab + i * DD, nullptr);
        gemm_kernel<<<ggrid, 256, 0, stream>>>(ab, Wq + i * DD * DD, bq + i * DD, qb,
                                               nullptr, nullptr, 0, BL, DD, DD);
        gemm_kernel<<<ggrid, 256, 0, stream>>>(seqs_embs, Wk + i * DD * DD, bk + i * DD, kb,
                                               tlf, nullptr, 0, BL, DD, DD);
        gemm_kernel<<<ggrid, 256, 0, stream>>>(seqs_embs, Wv + i * DD * DD, bv + i * DD, vb,
                                               tlf, nullptr, 0, BL, DD, DD);
        attn2_kernel<<<BB * HH, 256, ATTN_LDS_FLOATS * 4, stream>>>(qb, kb, vb, kmf, ab);
        ln_kernel<<<BL, 256, 0, stream>>>(ab, (i == 0) ? nullptr : tgt, tgt,
                                          lfg + i * DD, lfb + i * DD, nullptr);
        gemm_kernel<<<ggrid, 256, 0, stream>>>(tgt, W1 + i * DD * DD, b1 + i * DD, qb,
                                               nullptr, nullptr, 1, BL, DD, DD);
        gemm_kernel<<<ggrid, 256, 0, stream>>>(qb, W2 + i * DD * DD, b2 + i * DD, tgt,
                                               nullptr, keepf, 2, BL, DD, DD);
    }
    ln_kernel<<<BL, 256, 0, stream>>>(tgt, nullptr, out, llg, llb, keepf);
}

// Round 4
// 1592.906 us; speedup vs baseline: 5.3448x; 1.8006x over previous
//
#include <hip/hip_runtime.h>
#include <hip/hip_bf16.h>

#define BB 128
#define LL 200
#define DD 512
#define HH 8
#define DK 64
#define NBLK 2
#define BL (BB*LL)

typedef unsigned short ushort_t;
typedef __attribute__((ext_vector_type(8))) short short8;
typedef __attribute__((ext_vector_type(4))) float f32x4;

__device__ inline ushort_t f2b(float x) {
    unsigned u = __float_as_uint(x);
    unsigned r = (u + 0x7FFF + ((u >> 16) & 1)) >> 16;
    return (ushort_t)r;
}

__device__ inline void gload16(const void* g, void* l) {
    __builtin_amdgcn_global_load_lds((const __attribute__((address_space(1))) void*)g,
                                     (__attribute__((address_space(3))) void*)l,
                                     16, 0, 0);
}

// ---------------- masks ----------------
__global__ __launch_bounds__(256) void mask_kernel(const int* __restrict__ logs,
                                                   const int* __restrict__ entire,
                                                   float* __restrict__ tlf,
                                                   float* __restrict__ keepf,
                                                   float* __restrict__ kmf) {
    int i = blockIdx.x * 256 + threadIdx.x;
    if (i < BL) {
        float t = (logs[i] == 0) ? 1.f : 0.f;
        tlf[i] = t;
        keepf[i] = 1.f - t;
        kmf[i] = (logs[i] == 0 && entire[i] != 0) ? 1.f : 0.f;
    }
}

// target = seqs_embs * keep
__global__ __launch_bounds__(256) void init_target(const float* __restrict__ emb,
                                                   const float* __restrict__ keepf,
                                                   float* __restrict__ tgt) {
    int row = blockIdx.x;
    int t = threadIdx.x;
    float kf = keepf[row];
    size_t base = (size_t)row * DD;
    tgt[base + t] = emb[base + t] * kf;
    tgt[base + t + 256] = emb[base + t + 256] * kf;
}

// src_bf16 = emb * tl
__global__ __launch_bounds__(256) void src_kernel(const float* __restrict__ emb,
                                                  const float* __restrict__ tlf,
                                                  ushort_t* __restrict__ srcb) {
    int row = blockIdx.x;
    int t = threadIdx.x;
    float s = tlf[row];
    size_t base = (size_t)row * DD;
    srcb[base + t] = f2b(emb[base + t] * s);
    srcb[base + t + 256] = f2b(emb[base + t + 256] * s);
}

// weight transpose + bf16: Wt[n][k] = W[k][n]
__global__ __launch_bounds__(256) void wtrans_kernel(const float* __restrict__ W,
                                                     ushort_t* __restrict__ Wt) {
    __shared__ float ts[32][33];
    int tx = threadIdx.x & 31, ty = threadIdx.x >> 5;
    int bx = blockIdx.x * 32, by = blockIdx.y * 32;
    const float* Wm = W + (size_t)blockIdx.z * DD * DD;
    ushort_t* Wtm = Wt + (size_t)blockIdx.z * DD * DD;
    #pragma unroll
    for (int i = 0; i < 4; i++) {
        int r = ty + i * 8;
        ts[r][tx] = Wm[(size_t)(by + r) * DD + bx + tx];
    }
    __syncthreads();
    #pragma unroll
    for (int i = 0; i < 4; i++) {
        int r = ty + i * 8;
        Wtm[(size_t)(bx + r) * DD + by + tx] = f2b(ts[tx][r]);
    }
}

// ---------------- layernorm: optional fp32 out + optional bf16 out ----------------
__global__ __launch_bounds__(256) void ln_kernel(const float* __restrict__ x,
                                                 const float* __restrict__ addx,
                                                 float* __restrict__ outf,
                                                 ushort_t* __restrict__ outb,
                                                 const float* __restrict__ g,
                                                 const float* __restrict__ bt,
                                                 const float* __restrict__ keepf) {
    int row = blockIdx.x;
    int t = threadIdx.x;
    size_t base = (size_t)row * DD;
    float v0 = x[base + t], v1 = x[base + t + 256];
    if (addx) { v0 += addx[base + t]; v1 += addx[base + t + 256]; }
    float s = v0 + v1, sq = v0 * v0 + v1 * v1;
    #pragma unroll
    for (int off = 32; off; off >>= 1) {
        s += __shfl_xor(s, off);
        sq += __shfl_xor(sq, off);
    }
    __shared__ float rs[4], rq[4];
    int wid = t >> 6, lane = t & 63;
    if (lane == 0) { rs[wid] = s; rq[wid] = sq; }
    __syncthreads();
    s = rs[0] + rs[1] + rs[2] + rs[3];
    sq = rq[0] + rq[1] + rq[2] + rq[3];
    float mean = s * (1.f / DD);
    float var = sq * (1.f / DD) - mean * mean;
    float rstd = rsqrtf(fmaxf(var, 0.f) + 1e-8f);
    float kf = keepf ? keepf[row] : 1.f;
    float o0 = ((v0 - mean) * rstd * g[t] + bt[t]) * kf;
    float o1 = ((v1 - mean) * rstd * g[t + 256] + bt[t + 256]) * kf;
    if (outf) { outf[base + t] = o0; outf[base + t + 256] = o1; }
    if (outb) { outb[base + t] = f2b(o0); outb[base + t + 256] = f2b(o1); }
}

// ---------------- bf16 MFMA GEMM (m97 structure): C = A @ Wt^T + bias ----------------
// mode 0: Cf = acc+bias ; mode 1: Cb = bf16(relu(acc+bias)) ; mode 2: Cf = (Cf+acc+bias)*keepf
__global__ __launch_bounds__(256) void gemm_mfma(const ushort_t* __restrict__ A,
                                                 const ushort_t* __restrict__ Bt,
                                                 const float* __restrict__ bias,
                                                 float* __restrict__ Cf,
                                                 ushort_t* __restrict__ Cb,
                                                 const float* __restrict__ keepf,
                                                 int mode, int M, int N, int K) {
    __shared__ ushort_t sA[128 * 32];
    __shared__ ushort_t sB[128 * 32];
    int t = threadIdx.x;
    int w = t >> 6, lane = t & 63;
    int wm = w & 1, wn = w >> 1;
    int m0 = blockIdx.x * 128, n0 = blockIdx.y * 128;
    int lr = lane & 15, lq = lane >> 4;

    f32x4 acc[4][4] = {};

    for (int k0 = 0; k0 < K; k0 += 32) {
        #pragma unroll
        for (int r = 0; r < 2; r++) {
            int e = (r * 256 + t) * 8;
            int row = e >> 5, col = e & 31;
            gload16(A + (size_t)(m0 + row) * K + k0 + col, sA + (r * 256 + w * 64) * 8);
            gload16(Bt + (size_t)(n0 + row) * K + k0 + col, sB + (r * 256 + w * 64) * 8);
        }
        __syncthreads();

        short8 af[4], bf[4];
        #pragma unroll
        for (int mt = 0; mt < 4; mt++)
            af[mt] = *(const short8*)(sA + (wm * 64 + mt * 16 + lr) * 32 + lq * 8);
        #pragma unroll
        for (int nt = 0; nt < 4; nt++)
            bf[nt] = *(const short8*)(sB + (wn * 64 + nt * 16 + lr) * 32 + lq * 8);
        #pragma unroll
        for (int mt = 0; mt < 4; mt++)
            #pragma unroll
            for (int nt = 0; nt < 4; nt++)
                acc[mt][nt] = __builtin_amdgcn_mfma_f32_16x16x32_bf16(af[mt], bf[nt], acc[mt][nt], 0, 0, 0);
        __syncthreads();
    }

    #pragma unroll
    for (int nt = 0; nt < 4; nt++) {
        int col = n0 + wn * 64 + nt * 16 + lr;
        float bv = bias[col];
        #pragma unroll
        for (int mt = 0; mt < 4; mt++) {
            int rowb = m0 + wm * 64 + mt * 16 + lq * 4;
            #pragma unroll
            for (int r = 0; r < 4; r++) {
                int row = rowb + r;
                float o = acc[mt][nt][r] + bv;
                if (mode == 0) {
                    Cf[(size_t)row * N + col] = o;
                } else if (mode == 1) {
                    Cb[(size_t)row * N + col] = f2b(fmaxf(o, 0.f));
                } else {
                    float kf = keepf[row];
                    size_t idx = (size_t)row * N + col;
                    Cf[idx] = (Cf[idx] + o) * kf;
                }
            }
        }
    }
}

// ---------------- attention: one workgroup per (b,h); xout may alias q ----------------
#define ATTN_LDS_FLOATS 38864
__global__ __launch_bounds__(256, 1) void attn2_kernel(const float* __restrict__ q,
                                                       const float* __restrict__ k,
                                                       const float* __restrict__ v,
                                                       const float* __restrict__ kmf,
                                                       float* __restrict__ xout) {
    extern __shared__ float lds[];
    float* kT  = lds;             // [64][200]
    float* S   = lds + 12800;     // [200][64]
    float* shr = lds + 25600;     // qT[64][64] then V[200][64]
    float* kms = lds + 38400;     // [200]
    float* red = lds + 38608;     // [4][64]

    int t = threadIdx.x;
    int b = blockIdx.x >> 3;
    int h = blockIdx.x & 7;
    int tx = t & 15, ty = t >> 4;
    int wv = t >> 6, lane = t & 63;

    const float* kbase = k + (size_t)b * LL * DD + h * DK;
    const float* vbase = v + (size_t)b * LL * DD + h * DK;
    const float* qbase = q + (size_t)b * LL * DD + h * DK;
    float* obase = xout + (size_t)b * LL * DD + h * DK;

    for (int idx = t; idx < LL * 16; idx += 256) {
        int j = idx >> 4, dq = idx & 15;
        float4 kv = *(const float4*)(kbase + (size_t)j * DD + dq * 4);
        kT[(dq * 4 + 0) * 200 + j] = kv.x;
        kT[(dq * 4 + 1) * 200 + j] = kv.y;
        kT[(dq * 4 + 2) * 200 + j] = kv.z;
        kT[(dq * 4 + 3) * 200 + j] = kv.w;
    }
    if (t < LL) kms[t] = kmf[b * LL + t];
    __syncthreads();

    for (int qt = 0; qt < 4; qt++) {
        int q0 = qt * 64;
        int qn = (q0 + 64 <= LL) ? 64 : (LL - q0);
        for (int idx = t; idx < qn * 16; idx += 256) {
            int qi = idx >> 4, dq = idx & 15;
            float4 qv = *(const float4*)(qbase + (size_t)(q0 + qi) * DD + dq * 4);
            shr[(dq * 4 + 0) * 64 + qi] = qv.x;
            shr[(dq * 4 + 1) * 64 + qi] = qv.y;
            shr[(dq * 4 + 2) * 64 + qi] = qv.z;
            shr[(dq * 4 + 3) * 64 + qi] = qv.w;
        }
        __syncthreads();

        for (int jp = 0; jp < 4; jp++) {
            int j0 = jp * 64 + ty * 4;
            if (j0 < LL) {
                float acc[4][4] = {};
                #pragma unroll 4
                for (int d = 0; d < 64; d++) {
                    float4 a4 = *(const float4*)(kT + d * 200 + j0);
                    float4 b4 = *(const float4*)(shr + d * 64 + tx * 4);
                    float ar[4] = {a4.x, a4.y, a4.z, a4.w};
                    float br[4] = {b4.x, b4.y, b4.z, b4.w};
                    #pragma unroll
                    for (int i = 0; i < 4; i++)
                        #pragma unroll
                        for (int jj = 0; jj < 4; jj++)
                            acc[i][jj] = fmaf(ar[i], br[jj], acc[i][jj]);
                }
                #pragma unroll
                for (int i = 0; i < 4; i++) {
                    int j = j0 + i;
                    bool km = (kms[j] != 0.f);
                    int qg = q0 + tx * 4;
                    float4 o;
                    o.x = (km && j <= qg + 0) ? acc[i][0] * 0.125f : -1e9f;
                    o.y = (km && j <= qg + 1) ? acc[i][1] * 0.125f : -1e9f;
                    o.z = (km && j <= qg + 2) ? acc[i][2] * 0.125f : -1e9f;
                    o.w = (km && j <= qg + 3) ? acc[i][3] * 0.125f : -1e9f;
                    *(float4*)(S + j * 64 + tx * 4) = o;
                }
            }
        }
        __syncthreads();

        {
            int qi = lane;
            float mx = -3e38f;
            for (int j = wv; j < LL; j += 4) mx = fmaxf(mx, S[j * 64 + qi]);
            red[wv * 64 + qi] = mx;
            __syncthreads();
            mx = fmaxf(fmaxf(red[0 * 64 + qi], red[1 * 64 + qi]),
                       fmaxf(red[2 * 64 + qi], red[3 * 64 + qi]));
            __syncthreads();
            float sm = 0.f;
            for (int j = wv; j < LL; j += 4) {
                float e = __expf(S[j * 64 + qi] - mx);
                S[j * 64 + qi] = e;
                sm += e;
            }
            red[wv * 64 + qi] = sm;
            __syncthreads();
            sm = red[0 * 64 + qi] + red[1 * 64 + qi] + red[2 * 64 + qi] + red[3 * 64 + qi];
            float inv = (mx < -5e8f) ? 0.f : 1.f / sm;
            for (int j = wv; j < LL; j += 4) S[j * 64 + qi] *= inv;
        }
        __syncthreads();

        for (int idx = t; idx < LL * 16; idx += 256) {
            int j = idx >> 4, dq = idx & 15;
            float4 vvv = *(const float4*)(vbase + (size_t)j * DD + dq * 4);
            *(float4*)(shr + j * 64 + dq * 4) = vvv;
        }
        __syncthreads();

        {
            float acc[4][4] = {};
            #pragma unroll 4
            for (int j = 0; j < LL; j++) {
                float4 a4 = *(const float4*)(S + j * 64 + ty * 4);
                float4 b4 = *(const float4*)(shr + j * 64 + tx * 4);
                float ar[4] = {a4.x, a4.y, a4.z, a4.w};
                float br[4] = {b4.x, b4.y, b4.z, b4.w};
                #pragma unroll
                for (int i = 0; i < 4; i++)
                    #pragma unroll
                    for (int jj = 0; jj < 4; jj++)
                        acc[i][jj] = fmaf(ar[i], br[jj], acc[i][jj]);
            }
            #pragma unroll
            for (int i = 0; i < 4; i++) {
                int qi = ty * 4 + i;
                if (q0 + qi < LL) {
                    float4 o = {acc[i][0], acc[i][1], acc[i][2], acc[i][3]};
                    *(float4*)(obase + (size_t)(q0 + qi) * DD + tx * 4) = o;
                }
            }
        }
        __syncthreads();
    }
}

extern "C" void kernel_launch(void* const* d_in, const int* in_sizes, int n_in,
                              void* d_out, int out_size, void* d_ws, size_t ws_size,
                              hipStream_t stream) {
    const int* log_seqs = (const int*)d_in[0];
    const float* seqs_embs = (const float*)d_in[1];
    const int* entire = (const int*)d_in[2];
    const float* Wq = (const float*)d_in[3];
    const float* bq = (const float*)d_in[4];
    const float* Wk = (const float*)d_in[5];
    const float* bk = (const float*)d_in[6];
    const float* Wv = (const float*)d_in[7];
    const float* bv = (const float*)d_in[8];
    const float* lag = (const float*)d_in[9];
    const float* lab = (const float*)d_in[10];
    const float* lfg = (const float*)d_in[11];
    const float* lfb = (const float*)d_in[12];
    const float* W1 = (const float*)d_in[13];
    const float* b1 = (const float*)d_in[14];
    const float* W2 = (const float*)d_in[15];
    const float* b2 = (const float*)d_in[16];
    const float* llg = (const float*)d_in[17];
    const float* llb = (const float*)d_in[18];
    float* out = (float*)d_out;
    float* ws = (float*)d_ws;

    hipFuncSetAttribute((const void*)attn2_kernel,
                        hipFuncAttributeMaxDynamicSharedMemorySize,
                        ATTN_LDS_FLOATS * 4);

    // workspace budget (fits in < 242 MB; round-2's 262.45 MB was proven safe):
    // 4 fp32 act buffers (tgt,qb,kb,vb) + masks + srcb bf16 + 5 bf16 weight copies
    const size_t n = (size_t)BL * DD;
    float* tgt = ws;
    float* qb = ws + n;
    float* kb = ws + 2 * n;
    float* vb = ws + 3 * n;
    float* tlf = ws + 4 * n;
    float* keepf = tlf + BL;
    float* kmf = keepf + BL;
    ushort_t* srcb = (ushort_t*)(kmf + BL);
    ushort_t* WqT = srcb + n;
    ushort_t* WkT = WqT + (size_t)NBLK * DD * DD;
    ushort_t* WvT = WkT + (size_t)NBLK * DD * DD;
    ushort_t* W1T = WvT + (size_t)NBLK * DD * DD;
    ushort_t* W2T = W1T + (size_t)NBLK * DD * DD;
    // aliased bf16 activation buffers (stream-order lifetimes verified):
    ushort_t* lnb = (ushort_t*)vb;   // LN bf16 out: consumed before vb (re)written
    ushort_t* hb = (ushort_t*)qb;    // FFN1 out: qb dead after post-attn LN consumed it

    mask_kernel<<<(BL + 255) / 256, 256, 0, stream>>>(log_seqs, entire, tlf, keepf, kmf);
    init_target<<<BL, 256, 0, stream>>>(seqs_embs, keepf, tgt);
    src_kernel<<<BL, 256, 0, stream>>>(seqs_embs, tlf, srcb);
    dim3 tg(16, 16, NBLK);
    wtrans_kernel<<<tg, 256, 0, stream>>>(Wq, WqT);
    wtrans_kernel<<<tg, 256, 0, stream>>>(Wk, WkT);
    wtrans_kernel<<<tg, 256, 0, stream>>>(Wv, WvT);
    wtrans_kernel<<<tg, 256, 0, stream>>>(W1, W1T);
    wtrans_kernel<<<tg, 256, 0, stream>>>(W2, W2T);

    dim3 gg(BL / 128, DD / 128);
    for (int i = 0; i < NBLK; i++) {
        size_t wo = (size_t)i * DD * DD;
        // lnb = bf16(LN(tgt, ln_attn))
        ln_kernel<<<BL, 256, 0, stream>>>(tgt, nullptr, nullptr, lnb,
                                          lag + i * DD, lab + i * DD, nullptr);
        // q = lnb @ Wq + bq (fp32)
        gemm_mfma<<<gg, 256, 0, stream>>>(lnb, WqT + wo, bq + i * DD, qb, nullptr,
                                          nullptr, 0, BL, DD, DD);
        // k,v = srcb @ W + b (fp32)
        gemm_mfma<<<gg, 256, 0, stream>>>(srcb, WkT + wo, bk + i * DD, kb, nullptr,
                                          nullptr, 0, BL, DD, DD);
        gemm_mfma<<<gg, 256, 0, stream>>>(srcb, WvT + wo, bv + i * DD, vb, nullptr,
                                          nullptr, 0, BL, DD, DD);
        // attention, output in place over qb
        attn2_kernel<<<BB * HH, 256, ATTN_LDS_FLOATS * 4, stream>>>(qb, kb, vb, kmf, qb);
        // tgt = LN(qb (+tgt)), also bf16 copy lnb
        ln_kernel<<<BL, 256, 0, stream>>>(qb, (i == 0) ? nullptr : tgt, tgt, lnb,
                                          lfg + i * DD, lfb + i * DD, nullptr);
        // hb = bf16(relu(lnb @ W1 + b1))
        gemm_mfma<<<gg, 256, 0, stream>>>(lnb, W1T + wo, b1 + i * DD, nullptr, hb,
                                          nullptr, 1, BL, DD, DD);
        // tgt = (tgt + hb @ W2 + b2) * keep
        gemm_mfma<<<gg, 256, 0, stream>>>(hb, W2T + wo, b2 + i * DD, tgt, nullptr,
                                          keepf, 2, BL, DD, DD);
    }
    ln_kernel<<<BL, 256, 0, stream>>>(tgt, nullptr, out, nullptr, llg, llb, keepf);
}

// Round 5
// 1044.261 us; speedup vs baseline: 8.1529x; 1.5254x over previous
//
#include <hip/hip_runtime.h>
#include <hip/hip_bf16.h>

#define BB 128
#define LL 200
#define DD 512
#define HH 8
#define DK 64
#define NBLK 2
#define BL (BB*LL)

typedef unsigned short ushort_t;
typedef unsigned int uint_t;
typedef __attribute__((ext_vector_type(8))) short short8;
typedef __attribute__((ext_vector_type(4))) float f32x4;

__device__ inline ushort_t f2b(float x) {
    unsigned u = __float_as_uint(x);
    unsigned r = (u + 0x7FFF + ((u >> 16) & 1)) >> 16;
    return (ushort_t)r;
}

__device__ inline void gload16(const void* g, void* l) {
    __builtin_amdgcn_global_load_lds((const __attribute__((address_space(1))) void*)g,
                                     (__attribute__((address_space(3))) void*)l,
                                     16, 0, 0);
}

// ---------------- masks ----------------
__global__ __launch_bounds__(256) void mask_kernel(const int* __restrict__ logs,
                                                   const int* __restrict__ entire,
                                                   float* __restrict__ tlf,
                                                   float* __restrict__ keepf,
                                                   float* __restrict__ kmf) {
    int i = blockIdx.x * 256 + threadIdx.x;
    if (i < BL) {
        float t = (logs[i] == 0) ? 1.f : 0.f;
        tlf[i] = t;
        keepf[i] = 1.f - t;
        kmf[i] = (logs[i] == 0 && entire[i] != 0) ? 1.f : 0.f;
    }
}

// target = seqs_embs * keep
__global__ __launch_bounds__(256) void init_target(const float* __restrict__ emb,
                                                   const float* __restrict__ keepf,
                                                   float* __restrict__ tgt) {
    int row = blockIdx.x;
    int t = threadIdx.x;
    float kf = keepf[row];
    size_t base = (size_t)row * DD;
    tgt[base + t] = emb[base + t] * kf;
    tgt[base + t + 256] = emb[base + t + 256] * kf;
}

// src_bf16 = emb * tl
__global__ __launch_bounds__(256) void src_kernel(const float* __restrict__ emb,
                                                  const float* __restrict__ tlf,
                                                  ushort_t* __restrict__ srcb) {
    int row = blockIdx.x;
    int t = threadIdx.x;
    float s = tlf[row];
    size_t base = (size_t)row * DD;
    srcb[base + t] = f2b(emb[base + t] * s);
    srcb[base + t + 256] = f2b(emb[base + t + 256] * s);
}

// weight transpose + bf16: Wt[n][k] = W[k][n]
__global__ __launch_bounds__(256) void wtrans_kernel(const float* __restrict__ W,
                                                     ushort_t* __restrict__ Wt) {
    __shared__ float ts[32][33];
    int tx = threadIdx.x & 31, ty = threadIdx.x >> 5;
    int bx = blockIdx.x * 32, by = blockIdx.y * 32;
    const float* Wm = W + (size_t)blockIdx.z * DD * DD;
    ushort_t* Wtm = Wt + (size_t)blockIdx.z * DD * DD;
    #pragma unroll
    for (int i = 0; i < 4; i++) {
        int r = ty + i * 8;
        ts[r][tx] = Wm[(size_t)(by + r) * DD + bx + tx];
    }
    __syncthreads();
    #pragma unroll
    for (int i = 0; i < 4; i++) {
        int r = ty + i * 8;
        Wtm[(size_t)(bx + r) * DD + by + tx] = f2b(ts[tx][r]);
    }
}

// ---------------- layernorm ----------------
__global__ __launch_bounds__(256) void ln_kernel(const float* __restrict__ x,
                                                 const float* __restrict__ addx,
                                                 float* __restrict__ outf,
                                                 ushort_t* __restrict__ outb,
                                                 const float* __restrict__ g,
                                                 const float* __restrict__ bt,
                                                 const float* __restrict__ keepf) {
    int row = blockIdx.x;
    int t = threadIdx.x;
    size_t base = (size_t)row * DD;
    float v0 = x[base + t], v1 = x[base + t + 256];
    if (addx) { v0 += addx[base + t]; v1 += addx[base + t + 256]; }
    float s = v0 + v1, sq = v0 * v0 + v1 * v1;
    #pragma unroll
    for (int off = 32; off; off >>= 1) {
        s += __shfl_xor(s, off);
        sq += __shfl_xor(sq, off);
    }
    __shared__ float rs[4], rq[4];
    int wid = t >> 6, lane = t & 63;
    if (lane == 0) { rs[wid] = s; rq[wid] = sq; }
    __syncthreads();
    s = rs[0] + rs[1] + rs[2] + rs[3];
    sq = rq[0] + rq[1] + rq[2] + rq[3];
    float mean = s * (1.f / DD);
    float var = sq * (1.f / DD) - mean * mean;
    float rstd = rsqrtf(fmaxf(var, 0.f) + 1e-8f);
    float kf = keepf ? keepf[row] : 1.f;
    float o0 = ((v0 - mean) * rstd * g[t] + bt[t]) * kf;
    float o1 = ((v1 - mean) * rstd * g[t + 256] + bt[t + 256]) * kf;
    if (outf) { outf[base + t] = o0; outf[base + t + 256] = o1; }
    if (outb) { outb[base + t] = f2b(o0); outb[base + t + 256] = f2b(o1); }
}

// ---------------- bf16 MFMA GEMM: C = A @ Wt^T + bias ----------------
// mode 0: Cf = acc+bias ; mode 1: Cb = bf16(relu(acc+bias)) ;
// mode 2: Cf = (Cf+acc+bias)*keepf ; mode 3: Cb = bf16(acc+bias)
__global__ __launch_bounds__(256) void gemm_mfma(const ushort_t* __restrict__ A,
                                                 const ushort_t* __restrict__ Bt,
                                                 const float* __restrict__ bias,
                                                 float* __restrict__ Cf,
                                                 ushort_t* __restrict__ Cb,
                                                 const float* __restrict__ keepf,
                                                 int mode, int M, int N, int K) {
    __shared__ ushort_t sA[128 * 32];
    __shared__ ushort_t sB[128 * 32];
    int t = threadIdx.x;
    int w = t >> 6, lane = t & 63;
    int wm = w & 1, wn = w >> 1;
    int m0 = blockIdx.x * 128, n0 = blockIdx.y * 128;
    int lr = lane & 15, lq = lane >> 4;

    f32x4 acc[4][4] = {};

    for (int k0 = 0; k0 < K; k0 += 32) {
        #pragma unroll
        for (int r = 0; r < 2; r++) {
            int e = (r * 256 + t) * 8;
            int row = e >> 5, col = e & 31;
            gload16(A + (size_t)(m0 + row) * K + k0 + col, sA + (r * 256 + w * 64) * 8);
            gload16(Bt + (size_t)(n0 + row) * K + k0 + col, sB + (r * 256 + w * 64) * 8);
        }
        __syncthreads();

        short8 af[4], bf[4];
        #pragma unroll
        for (int mt = 0; mt < 4; mt++)
            af[mt] = *(const short8*)(sA + (wm * 64 + mt * 16 + lr) * 32 + lq * 8);
        #pragma unroll
        for (int nt = 0; nt < 4; nt++)
            bf[nt] = *(const short8*)(sB + (wn * 64 + nt * 16 + lr) * 32 + lq * 8);
        #pragma unroll
        for (int mt = 0; mt < 4; mt++)
            #pragma unroll
            for (int nt = 0; nt < 4; nt++)
                acc[mt][nt] = __builtin_amdgcn_mfma_f32_16x16x32_bf16(af[mt], bf[nt], acc[mt][nt], 0, 0, 0);
        __syncthreads();
    }

    #pragma unroll
    for (int nt = 0; nt < 4; nt++) {
        int col = n0 + wn * 64 + nt * 16 + lr;
        float bv = bias[col];
        #pragma unroll
        for (int mt = 0; mt < 4; mt++) {
            int rowb = m0 + wm * 64 + mt * 16 + lq * 4;
            #pragma unroll
            for (int r = 0; r < 4; r++) {
                int row = rowb + r;
                float o = acc[mt][nt][r] + bv;
                size_t idx = (size_t)row * N + col;
                if (mode == 0) {
                    Cf[idx] = o;
                } else if (mode == 1) {
                    Cb[idx] = f2b(fmaxf(o, 0.f));
                } else if (mode == 3) {
                    Cb[idx] = f2b(o);
                } else {
                    float kf = keepf[row];
                    Cf[idx] = (Cf[idx] + o) * kf;
                }
            }
        }
    }
}

// ---------------- attention v3: MFMA, one workgroup per (b,h) ----------------
// LDS (ushort offsets): sK[256*72] @0 | sVt[64*264] @18432 | sP[64*264] @35328 |
// sQ[64*72] @52224 | floats @ushort 56832: kms[256], redm[256], reds[256]
#define ATTN3_LDS_BYTES 116736
__global__ __launch_bounds__(256, 1) void attn3_kernel(const ushort_t* __restrict__ q,
                                                       const ushort_t* __restrict__ k,
                                                       const ushort_t* __restrict__ v,
                                                       const float* __restrict__ kmf,
                                                       float* __restrict__ xout) {
    extern __shared__ ushort_t su[];
    ushort_t* sK = su;                 // [256][72] keys x d (B-layout for QK^T)
    ushort_t* sVt = su + 18432;        // [64][264]  d x keys (B-layout for PV)
    ushort_t* sP = su + 35328;         // [64][264]  q x keys (A-layout for PV)
    ushort_t* sQ = su + 52224;         // [64][72]   q x d (A-layout for QK^T)
    float* fl = (float*)(su + 56832);
    float* kms = fl;                   // [256]
    float* redm = fl + 256;            // [4][64]
    float* reds = fl + 512;            // [4][64]

    int t = threadIdx.x;
    int b = blockIdx.x >> 3, h = blockIdx.x & 7;
    int w = t >> 6, lane = t & 63;
    int lr = lane & 15, lq = lane >> 4;

    const ushort_t* kg = k + (size_t)b * LL * DD + h * DK;
    const ushort_t* vg = v + (size_t)b * LL * DD + h * DK;
    const ushort_t* qg = q + (size_t)b * LL * DD + h * DK;
    float* og = xout + (size_t)b * LL * DD + h * DK;

    // stage K [200][64] -> sK, pitch 72 (2-way bank alias = free)
    for (int idx = t; idx < 1600; idx += 256) {
        int row = idx >> 3, seg = idx & 7;
        uint4 kv = *(const uint4*)(kg + (size_t)row * DD + seg * 8);
        *(uint4*)(sK + row * 72 + seg * 8) = kv;
    }
    // stage V^T (pairs of keys packed per b32 write) + zero-fill keys 200..255
    for (int idx = t; idx < 1024; idx += 256) {
        int s = idx >> 7, tt = idx & 127;
        int j0 = tt * 2;
        uint_t outw[8];
        if (j0 < LL) {
            uint4 a = *(const uint4*)(vg + (size_t)j0 * DD + s * 8);
            uint4 c = *(const uint4*)(vg + (size_t)(j0 + 1) * DD + s * 8);
            uint_t av[4] = {a.x, a.y, a.z, a.w};
            uint_t cv[4] = {c.x, c.y, c.z, c.w};
            #pragma unroll
            for (int i = 0; i < 8; i++) {
                uint_t lo = (av[i >> 1] >> ((i & 1) * 16)) & 0xFFFFu;
                uint_t hi = (cv[i >> 1] >> ((i & 1) * 16)) & 0xFFFFu;
                outw[i] = lo | (hi << 16);
            }
        } else {
            #pragma unroll
            for (int i = 0; i < 8; i++) outw[i] = 0;
        }
        #pragma unroll
        for (int i = 0; i < 8; i++)
            ((uint_t*)sVt)[(s * 8 + i) * 132 + tt] = outw[i];
    }
    kms[t] = (t < LL) ? kmf[b * LL + t] : 0.f;
    __syncthreads();

    for (int qt = 0; qt < 4; qt++) {
        int q0 = qt * 64;
        // stage Q tile (row clamped; out-of-range queries never stored)
        for (int idx = t; idx < 512; idx += 256) {
            int qi = idx >> 3, seg = idx & 7;
            int grow = q0 + qi; if (grow > LL - 1) grow = LL - 1;
            uint4 qv = *(const uint4*)(qg + (size_t)grow * DD + seg * 8);
            *(uint4*)(sQ + qi * 72 + seg * 8) = qv;
        }
        __syncthreads();

        // S = Q @ K^T ; wave w covers keys w*64..w*64+63
        f32x4 accS[4][4] = {};
        #pragma unroll
        for (int ks = 0; ks < 2; ks++) {
            short8 af[4], bf[4];
            #pragma unroll
            for (int mt = 0; mt < 4; mt++)
                af[mt] = *(const short8*)(sQ + (mt * 16 + lr) * 72 + ks * 32 + lq * 8);
            #pragma unroll
            for (int nt = 0; nt < 4; nt++)
                bf[nt] = *(const short8*)(sK + (w * 64 + nt * 16 + lr) * 72 + ks * 32 + lq * 8);
            #pragma unroll
            for (int mt = 0; mt < 4; mt++)
                #pragma unroll
                for (int nt = 0; nt < 4; nt++)
                    accS[mt][nt] = __builtin_amdgcn_mfma_f32_16x16x32_bf16(af[mt], bf[nt], accS[mt][nt], 0, 0, 0);
        }

        // mask + scale (predicated: kills any garbage in padded key rows)
        float km[4];
        #pragma unroll
        for (int nt = 0; nt < 4; nt++) km[nt] = kms[w * 64 + nt * 16 + lr];
        float rmax[4][4];
        #pragma unroll
        for (int mt = 0; mt < 4; mt++) {
            #pragma unroll
            for (int r = 0; r < 4; r++) {
                int qrow = q0 + mt * 16 + lq * 4 + r;
                float m = -1e9f;
                #pragma unroll
                for (int nt = 0; nt < 4; nt++) {
                    int j = w * 64 + nt * 16 + lr;
                    bool ok = (j <= qrow) && (km[nt] != 0.f);
                    float s = ok ? accS[mt][nt][r] * 0.125f : -1e9f;
                    accS[mt][nt][r] = s;
                    m = fmaxf(m, s);
                }
                #pragma unroll
                for (int off = 1; off < 16; off <<= 1)
                    m = fmaxf(m, __shfl_xor(m, off));
                rmax[mt][r] = m;
            }
        }
        if (lr == 0) {
            #pragma unroll
            for (int mt = 0; mt < 4; mt++)
                #pragma unroll
                for (int r = 0; r < 4; r++)
                    redm[w * 64 + mt * 16 + lq * 4 + r] = rmax[mt][r];
        }
        __syncthreads();

        // exp + row-sum
        float gmx[4][4], rsum[4][4];
        #pragma unroll
        for (int mt = 0; mt < 4; mt++) {
            #pragma unroll
            for (int r = 0; r < 4; r++) {
                int row = mt * 16 + lq * 4 + r;
                float gm = fmaxf(fmaxf(redm[row], redm[64 + row]),
                                 fmaxf(redm[128 + row], redm[192 + row]));
                gmx[mt][r] = gm;
                float ps = 0.f;
                #pragma unroll
                for (int nt = 0; nt < 4; nt++) {
                    float e = __expf(accS[mt][nt][r] - gm);
                    accS[mt][nt][r] = e;
                    ps += e;
                }
                #pragma unroll
                for (int off = 1; off < 16; off <<= 1)
                    ps += __shfl_xor(ps, off);
                rsum[mt][r] = ps;
            }
        }
        if (lr == 0) {
            #pragma unroll
            for (int mt = 0; mt < 4; mt++)
                #pragma unroll
                for (int r = 0; r < 4; r++)
                    reds[w * 64 + mt * 16 + lq * 4 + r] = rsum[mt][r];
        }
        __syncthreads();

        // normalize, bf16, write P (A-layout). all-masked row -> inv=0 -> exact zeros
        #pragma unroll
        for (int mt = 0; mt < 4; mt++) {
            #pragma unroll
            for (int r = 0; r < 4; r++) {
                int row = mt * 16 + lq * 4 + r;
                float tot = reds[row] + reds[64 + row] + reds[128 + row] + reds[192 + row];
                float inv = (gmx[mt][r] < -5e8f) ? 0.f : 1.f / tot;
                #pragma unroll
                for (int nt = 0; nt < 4; nt++)
                    sP[row * 264 + w * 64 + nt * 16 + lr] = f2b(accS[mt][nt][r] * inv);
            }
        }
        __syncthreads();

        // O = P @ V ; wave w covers d-tile w*16..w*16+15
        f32x4 accO[4] = {};
        #pragma unroll
        for (int ks2 = 0; ks2 < 8; ks2++) {
            short8 bfv = *(const short8*)(sVt + (w * 16 + lr) * 264 + ks2 * 32 + lq * 8);
            #pragma unroll
            for (int mt = 0; mt < 4; mt++) {
                short8 afp = *(const short8*)(sP + (mt * 16 + lr) * 264 + ks2 * 32 + lq * 8);
                accO[mt] = __builtin_amdgcn_mfma_f32_16x16x32_bf16(afp, bfv, accO[mt], 0, 0, 0);
            }
        }
        #pragma unroll
        for (int mt = 0; mt < 4; mt++) {
            #pragma unroll
            for (int r = 0; r < 4; r++) {
                int row = q0 + mt * 16 + lq * 4 + r;
                if (row < LL)
                    og[(size_t)row * DD + w * 16 + lr] = accO[mt][r];
            }
        }
        __syncthreads();
    }
}

extern "C" void kernel_launch(void* const* d_in, const int* in_sizes, int n_in,
                              void* d_out, int out_size, void* d_ws, size_t ws_size,
                              hipStream_t stream) {
    const int* log_seqs = (const int*)d_in[0];
    const float* seqs_embs = (const float*)d_in[1];
    const int* entire = (const int*)d_in[2];
    const float* Wq = (const float*)d_in[3];
    const float* bq = (const float*)d_in[4];
    const float* Wk = (const float*)d_in[5];
    const float* bk = (const float*)d_in[6];
    const float* Wv = (const float*)d_in[7];
    const float* bv = (const float*)d_in[8];
    const float* lag = (const float*)d_in[9];
    const float* lab = (const float*)d_in[10];
    const float* lfg = (const float*)d_in[11];
    const float* lfb = (const float*)d_in[12];
    const float* W1 = (const float*)d_in[13];
    const float* b1 = (const float*)d_in[14];
    const float* W2 = (const float*)d_in[15];
    const float* b2 = (const float*)d_in[16];
    const float* llg = (const float*)d_in[17];
    const float* llb = (const float*)d_in[18];
    float* out = (float*)d_out;
    float* ws = (float*)d_ws;

    hipFuncSetAttribute((const void*)attn3_kernel,
                        hipFuncAttributeMaxDynamicSharedMemorySize,
                        ATTN3_LDS_BYTES);

    // workspace ~215 MB (< 241 MB proven safe):
    // tgt f32 | aout f32 | srcb,qb,kb,vb bf16 | 5 bf16 weights | masks
    const size_t n = (size_t)BL * DD;
    float* tgt = ws;
    float* aout = ws + n;
    ushort_t* srcb = (ushort_t*)(ws + 2 * n);
    ushort_t* qb = srcb + n;
    ushort_t* kb = qb + n;
    ushort_t* vb = kb + n;
    ushort_t* WqT = vb + n;
    ushort_t* WkT = WqT + (size_t)NBLK * DD * DD;
    ushort_t* WvT = WkT + (size_t)NBLK * DD * DD;
    ushort_t* W1T = WvT + (size_t)NBLK * DD * DD;
    ushort_t* W2T = W1T + (size_t)NBLK * DD * DD;
    float* tlf = (float*)(W2T + (size_t)NBLK * DD * DD);
    float* keepf = tlf + BL;
    float* kmf = keepf + BL;
    // aliases (stream-order lifetimes audited):
    ushort_t* lnb = vb;   // LN bf16 out: dead before V GEMM rewrites vb / after FFN1
    ushort_t* hb = qb;    // FFN1 out: qb dead after attention

    mask_kernel<<<(BL + 255) / 256, 256, 0, stream>>>(log_seqs, entire, tlf, keepf, kmf);
    init_target<<<BL, 256, 0, stream>>>(seqs_embs, keepf, tgt);
    src_kernel<<<BL, 256, 0, stream>>>(seqs_embs, tlf, srcb);
    dim3 tg(16, 16, NBLK);
    wtrans_kernel<<<tg, 256, 0, stream>>>(Wq, WqT);
    wtrans_kernel<<<tg, 256, 0, stream>>>(Wk, WkT);
    wtrans_kernel<<<tg, 256, 0, stream>>>(Wv, WvT);
    wtrans_kernel<<<tg, 256, 0, stream>>>(W1, W1T);
    wtrans_kernel<<<tg, 256, 0, stream>>>(W2, W2T);

    dim3 gg(BL / 128, DD / 128);
    for (int i = 0; i < NBLK; i++) {
        size_t wo = (size_t)i * DD * DD;
        // lnb = bf16(LN(tgt, ln_attn))
        ln_kernel<<<BL, 256, 0, stream>>>(tgt, nullptr, nullptr, lnb,
                                          lag + i * DD, lab + i * DD, nullptr);
        // q,k,v projections -> bf16
        gemm_mfma<<<gg, 256, 0, stream>>>(lnb, WqT + wo, bq + i * DD, nullptr, qb,
                                          nullptr, 3, BL, DD, DD);
        gemm_mfma<<<gg, 256, 0, stream>>>(srcb, WkT + wo, bk + i * DD, nullptr, kb,
                                          nullptr, 3, BL, DD, DD);
        gemm_mfma<<<gg, 256, 0, stream>>>(srcb, WvT + wo, bv + i * DD, nullptr, vb,
                                          nullptr, 3, BL, DD, DD);
        // attention (MFMA) -> aout fp32
        attn3_kernel<<<BB * HH, 256, ATTN3_LDS_BYTES, stream>>>(qb, kb, vb, kmf, aout);
        // tgt = LN(aout (+tgt)), bf16 copy to lnb
        ln_kernel<<<BL, 256, 0, stream>>>(aout, (i == 0) ? nullptr : tgt, tgt, lnb,
                                          lfg + i * DD, lfb + i * DD, nullptr);
        // hb = bf16(relu(lnb @ W1 + b1))
        gemm_mfma<<<gg, 256, 0, stream>>>(lnb, W1T + wo, b1 + i * DD, nullptr, hb,
                                          nullptr, 1, BL, DD, DD);
        // tgt = (tgt + hb @ W2 + b2) * keep
        gemm_mfma<<<gg, 256, 0, stream>>>(hb, W2T + wo, b2 + i * DD, tgt, nullptr,
                                          keepf, 2, BL, DD, DD);
    }
    ln_kernel<<<BL, 256, 0, stream>>>(tgt, nullptr, out, nullptr, llg, llb, keepf);
}